// Round 8
// baseline (92.251 us; speedup 1.0000x reference)
//
#include <hip/hip_runtime.h>
#include <cstdint>

// Local NN VOS features via banded single-plane-i8 MFMA GEMM. MI355X round 16.
//
// d(i,j,o) = min over |dy|<=15,|dx|<=15 of (in-frame && label==gt[o] ? ||Q-P||^2 : 1.0)
//          = clamp( min_valid( x2 + y2 - 2 Q.P ), 0, 1.0 )
//
// Round-16 changes vs round 15 (90.7 us; traffic knobs stopped mattering):
//   POST-MORTEM r15: r13 calibration (119.4 = fill 42 + band 53 + ~24) implies band
//   still ~25 us vs a ~5 us throughput model -> LATENCY-bound: the harness's 256 MiB
//   poison fill evicts the ENTIRE L3 each iteration, so band's Pq/yl/Q reads are
//   L3/HBM-latency (~500-900 cyc); grid 512 = 2 blocks/CU (the (256,4) VGPR cap of
//   128 bought nothing); VGPR_Count 64 shows the compiler kept ~no loads in flight:
//   ~15 serial load->mfma->min rounds/wave ~= 20-30 us. Matches.
//   FIX (pure MLP, zero structural change):
//     - loops swapped (t outer, pair inner); ALL <=24 loads of a t-slice issued
//       up front (4 pairs x {4 B-frags + 2 yl}); addresses row-clamped so every
//       load is in-bounds and unconditional; compute keeps exact pv/hasB/tri masks.
//     - __launch_bounds__(256,2): grid gives 2 blocks/CU anyway -> VGPR cap 256,
//       buffers live in registers at zero occupancy cost.
//   Kept: block=(q-row i, col-quarter qc) exclusive ownership (no atomics/fences),
//   waves split 31 p-rows 8/8/8/7, A-side self-quant from Q (r15), B direct loads
//   (no LDS staging), LDS = 1.5 KB merge + 128 B x2, plain single stores.
// Precision: single-plane i8 (q ~ h/32); dot err sigma ~0.13 vs ~45 budget. Sentinels:
// PEN_NM=2^22 > max|C|~1.6M scaled; masked C -> -2^28; mm init 2^30 (no i32 overflow).
//
// Workspace: yl 128K + Pq 2.10M ~= 2.23 MB.

#define HW   128
#define NC   100
#define MD   15
#define NOBJ 3
#define PIX  (HW * HW)
#define NOUT (PIX * NOBJ)          // 49152
#define PEN_NM (1 << 22)           // non-match penalty (units 1/512): > max |C| + 512
#define CSENT  (1 << 28)           // masked-slot C sentinel (subtracted -> huge cand)
#define IINIT  (1 << 30)           // running-min init

typedef __attribute__((ext_vector_type(4))) int intx4;   // 16 i8 / 4 i32 (MFMA A/B/C)

// h = rne(x*32) clamped to [-127,127]
__device__ inline intx4 quant_pack16(const float* v) {
    signed char b[16];
#pragma unroll
    for (int j = 0; j < 16; ++j) {
        int qi = __float2int_rn(v[j] * 32.f);
        b[j] = (signed char)max(-127, min(127, qi));
    }
    intx4 r;
#pragma unroll
    for (int w = 0; w < 4; ++w)
        r[w] = (b[4*w] & 255) | ((b[4*w+1] & 255) << 8) |
               ((b[4*w+2] & 255) << 16) | ((b[4*w+3] & 255) << 24);
    return r;
}

// ---------------- prep: quantize P (B image) + (y2,label) pairs only --------------
// Grid 512 x 256 (2048 waves); wave = 8 pixels.
__global__ __launch_bounds__(256) void vos_prep(
    const float* __restrict__ P, const int* __restrict__ labels,
    signed char* __restrict__ Pq, int2* __restrict__ yl)
{
    const int lane = threadIdx.x & 63;
    const int wid  = blockIdx.x * 4 + (threadIdx.x >> 6);   // 0..2047

    // ---- P: wave = 8 pixels; lane = (pix8: lane>>3, chunk c: lane&7), k=c*16..+15
    const int pix = wid * 8 + (lane >> 3);
    const int c = lane & 7;
    const float* sp = P + (size_t)pix * NC;
    const int k0 = c * 16;
    float v[16];
#pragma unroll
    for (int c4 = 0; c4 < 4; ++c4) {
        float4 a = {0.f,0.f,0.f,0.f};
        if (k0 + c4 * 4 + 4 <= NC) a = *(const float4*)(sp + k0 + c4 * 4);
        v[c4*4+0]=a.x; v[c4*4+1]=a.y; v[c4*4+2]=a.z; v[c4*4+3]=a.w;
    }
    // B-image: pixel block 128 B = [chunk c : 8][16 i8] (linear)
    *(intx4*)(Pq + (size_t)pix * 128 + (c << 4)) = quant_pack16(v);
    float part = 0.f;                       // exact fp32 |p|^2
#pragma unroll
    for (int j = 0; j < 16; ++j) part = fmaf(v[j], v[j], part);
    part += __shfl_xor(part, 1); part += __shfl_xor(part, 2); part += __shfl_xor(part, 4);
    if ((lane & 7) == 0)
        yl[pix] = make_int2(__float2int_rn(part * 512.f), labels[pix]);  // (y2 in 1/512, label)
}

// ---------------- main: banded i8-MFMA GEMM, exclusive output ownership -----------
// Block = (q-row i, col-quarter qc): outputs (i, [32qc,32qc+32), 0..2) written ONCE.
// A-side self-served (in-register quant); waves split the 31 p-rows 8/8/8/7.
// Inner structure: t outer, pairs inner; all <=24 loads of a t-slice issued UP FRONT
// (row-clamped, unconditional) for max memory-level parallelism; compute masked by
// pv/hasB/tri exactly as before. Grid 512 = 8 XCDs x 16 rows x 4 quarters.
__global__ __launch_bounds__(256, 2) void vos_band(
    const signed char* __restrict__ Pq, const float* __restrict__ Q,
    const int2* __restrict__ yl, const int* __restrict__ gt,
    float* __restrict__ out)
{
    __shared__ int   ps[4][96];              // per-wave partial mins (1.5 KB)
    __shared__ float xs[32];                 // |q|^2 for the block's 32 cols

    const int tid  = threadIdx.x;
    const int lane = tid & 63;
    const int wv   = tid >> 6;               // 0..3
    const int quad = lane >> 4;
    const int n    = lane & 15;

    // XCD grouping: xcd = b&7 gets 16 contiguous q-rows (all 4 col-quarters)
    const int b   = blockIdx.x;
    const int xcd = b & 7;
    const int idx = b >> 3;                  // 0..63
    const int i   = xcd * 16 + (idx & 15);   // q-row 0..127
    const int qc  = idx >> 4;                // col-quarter 0..3
    const int j0  = qc * 32;

    // wave's p-row range within [i-15, i+15], clipped to frame
    const int rb0  = i - MD + wv * 8;
    const int rcnt = (wv == 3) ? 7 : 8;
    const int rlo  = max(rb0, 0);
    const int rhi  = min(rb0 + rcnt, HW);

    const int g0 = gt[0], g1 = gt[1], g2 = gt[2];

    // ---- A-side self-quant: lane (quad,n) serves pixel col j0+uc*16+n, channels
    // k0 = kh*64 + quad*16 .. +15. Identical numerics to prep's old Q path.
    intx4 Af[2][2];                          // [uc][kh]
    float x2q[2];
#pragma unroll
    for (int uc = 0; uc < 2; ++uc) {
        const int col = j0 + uc * 16 + n;
        const float* sp = Q + (size_t)(i * HW + col) * NC;
        float acc = 0.f;
#pragma unroll
        for (int kh = 0; kh < 2; ++kh) {
            const int k0 = kh * 64 + quad * 16;
            float v[16];
#pragma unroll
            for (int c4 = 0; c4 < 4; ++c4) {
                float4 a = {0.f,0.f,0.f,0.f};
                if (k0 + c4 * 4 + 4 <= NC) a = *(const float4*)(sp + k0 + c4 * 4);
                v[c4*4+0]=a.x; v[c4*4+1]=a.y; v[c4*4+2]=a.z; v[c4*4+3]=a.w;
            }
#pragma unroll
            for (int j = 0; j < 16; ++j) acc = fmaf(v[j], v[j], acc);
            Af[uc][kh] = quant_pack16(v);
        }
        acc += __shfl_xor(acc, 16); acc += __shfl_xor(acc, 32);
        x2q[uc] = acc;
    }
    if (wv == 0 && lane < 16) {              // quad-0 lanes publish x2 for finalize
        xs[lane]      = x2q[0];
        xs[lane + 16] = x2q[1];
    }

    // Band masks for triangular side tiles: dx = 16*du + n - m, valid |dx|<=15.
    bool bgt[4], blt[4];
#pragma unroll
    for (int reg = 0; reg < 4; ++reg) {
        int m = quad * 4 + reg;
        bgt[reg] = n > m;   // du = -1
        blt[reg] = n < m;   // du = +1
    }

    // Integer running mins of (pen*512 - C) per object (C = 1024*dot; scale 1/512).
    int mm[2][4][NOBJ];
#pragma unroll
    for (int uc = 0; uc < 2; ++uc)
#pragma unroll
    for (int reg = 0; reg < 4; ++reg) {
        mm[uc][reg][0] = IINIT; mm[uc][reg][1] = IINIT; mm[uc][reg][2] = IINIT;
    }

#pragma unroll
    for (int t = 0; t < 4; ++t) {
        const int base = j0 + 16 * (t - 1);
        if (base < 0 || base >= HW) continue;          // frame clip (qc0/t0, qc3/t3)
        const int pcol = base + n;
        const int offk0 = pcol * 128 + (quad << 4);          // kh = 0
        const int offk1 = pcol * 128 + ((4 + quad) << 4);    // kh = 1

        // ---- issue ALL loads for this t-slice (4 pairs x {4 B + 2 yl}), clamped
        intx4 bvA[4][2], bvB[4][2];
        int2  ylA[4], ylB[4];
#pragma unroll
        for (int pi = 0; pi < 4; ++pi) {
            const int ra = min(max(rlo + 2 * pi, 0), HW - 1);  // clamped: always in-bounds
            const int rb = min(ra + 1, HW - 1);
            const signed char* BA = Pq + (size_t)ra * 16384;
            const signed char* BB = Pq + (size_t)rb * 16384;
            bvA[pi][0] = *(const intx4*)(BA + offk0);
            bvA[pi][1] = *(const intx4*)(BA + offk1);
            bvB[pi][0] = *(const intx4*)(BB + offk0);
            bvB[pi][1] = *(const intx4*)(BB + offk1);
            ylA[pi] = yl[ra * HW + pcol];
            ylB[pi] = yl[rb * HW + pcol];
        }

        // ---- compute the 4 pairs with exact pv/hasB masking
#pragma unroll
        for (int pi = 0; pi < 4; ++pi) {
            const int ra = rlo + 2 * pi;
            const bool pv   = ra < rhi;                // pair valid (wave-uniform)
            const bool hasB = (ra + 1) < rhi;
            if (!pv) continue;

            int pA0 = (ylA[pi].y == g0) ? ylA[pi].x : PEN_NM;
            int pA1 = (ylA[pi].y == g1) ? ylA[pi].x : PEN_NM;
            int pA2 = (ylA[pi].y == g2) ? ylA[pi].x : PEN_NM;
            int pB0 = (ylB[pi].y == g0) ? ylB[pi].x : PEN_NM;
            int pB1 = (ylB[pi].y == g1) ? ylB[pi].x : PEN_NM;
            int pB2 = (ylB[pi].y == g2) ? ylB[pi].x : PEN_NM;

            intx4 CA[2], CB[2];
#pragma unroll
            for (int uc = 0; uc < 2; ++uc) {
                CA[uc] = (intx4){0,0,0,0};
                CB[uc] = (intx4){0,0,0,0};
            }
#pragma unroll
            for (int kh = 0; kh < 2; ++kh) {
#pragma unroll
                for (int uc = 0; uc < 2; ++uc) {
                    if (uc == 0 && t == 3) continue;   // uc0 uses t in {0,1,2}
                    if (uc == 1 && t == 0) continue;   // uc1 uses t in {1,2,3}
                    CA[uc] = __builtin_amdgcn_mfma_i32_16x16x64_i8(Af[uc][kh], bvA[pi][kh], CA[uc], 0, 0, 0);
                    CB[uc] = __builtin_amdgcn_mfma_i32_16x16x64_i8(Af[uc][kh], bvB[pi][kh], CB[uc], 0, 0, 0);
                }
            }

            // ---- epilogue: cand = pen - C (1/512 units); both rows -> min3 chain
#pragma unroll
            for (int uc = 0; uc < 2; ++uc) {
                if (uc == 0 && t == 3) continue;
                if (uc == 1 && t == 0) continue;
                const int du = t - 1 - uc;             // -1, 0, +1 (compile-time)
#pragma unroll
                for (int reg = 0; reg < 4; ++reg) {
                    bool tri = (du == 0) | (du == -1 ? bgt[reg] : blt[reg]);
                    bool okB = hasB & tri;
                    int cA = tri ? CA[uc][reg] : -CSENT;
                    int cB = okB ? CB[uc][reg] : -CSENT;
                    mm[uc][reg][0] = min(min(mm[uc][reg][0], pA0 - cA), pB0 - cB);
                    mm[uc][reg][1] = min(min(mm[uc][reg][1], pA1 - cA), pB1 - cB);
                    mm[uc][reg][2] = min(min(mm[uc][reg][2], pA2 - cA), pB2 - cB);
                }
            }
        }
    }

    // ---- min-reduce across the 16 N-lanes (int butterfly; reduces over p-cols)
#pragma unroll
    for (int s = 1; s < 16; s <<= 1) {
#pragma unroll
        for (int uc = 0; uc < 2; ++uc)
#pragma unroll
        for (int reg = 0; reg < 4; ++reg)
#pragma unroll
        for (int o = 0; o < NOBJ; ++o)
            mm[uc][reg][o] = min(mm[uc][reg][o], __shfl_xor(mm[uc][reg][o], s));
    }

    // ---- cross-wave merge in LDS (exact int min), finalize, single plain store
    if (n == 0) {
#pragma unroll
        for (int uc = 0; uc < 2; ++uc)
#pragma unroll
        for (int reg = 0; reg < 4; ++reg) {
            const int cl = 16 * uc + 4 * quad + reg;   // 0..31 within quarter
#pragma unroll
            for (int o = 0; o < NOBJ; ++o)
                ps[wv][cl * 3 + o] = mm[uc][reg][o];
        }
    }
    __syncthreads();
    if (tid < 96) {
        int v = min(min(ps[0][tid], ps[1][tid]), min(ps[2][tid], ps[3][tid]));
        float val = (float)v * (1.f / 512.f) + xs[tid / 3];         // exact |q|^2
        out[(size_t)(i * HW + j0) * 3 + tid] = fminf(fmaxf(val, 0.f), 1.0f);  // 1.0 = pad
    }
}

extern "C" void kernel_launch(void* const* d_in, const int* in_sizes, int n_in,
                              void* d_out, int out_size, void* d_ws, size_t ws_size,
                              hipStream_t stream) {
    const float* P      = (const float*)d_in[0];   // prev_frame_embedding [128,128,100]
    const float* Q      = (const float*)d_in[1];   // query_embedding      [128,128,100]
    const int*   labels = (const int*)d_in[2];     // prev_frame_labels    [128,128,1]
    const int*   gt     = (const int*)d_in[3];     // gt_ids [3]
    // d_in[4] = max_distance (always 15; compiled for MD=15)

    // Workspace layout (~2.23 MB):
    int2*  yl = (int2*)d_ws;                                    // 128 KB (y2*512, label)
    signed char* Pq = (signed char*)(yl + PIX);                 // 2.10 MB (B image)
    float* out = (float*)d_out;

    vos_prep<<<512, 256, 0, stream>>>(P, labels, Pq, yl);
    vos_band<<<512, 256, 0, stream>>>(Pq, Q, yl, gt, out);
}

// Round 9
// 86.844 us; speedup vs baseline: 1.0623x; 1.0623x over previous
//
#include <hip/hip_runtime.h>
#include <cstdint>

// Local NN VOS features via banded single-plane-i8 MFMA GEMM. MI355X round 17.
//
// d(i,j,o) = min over |dy|<=15,|dx|<=15 of (in-frame && label==gt[o] ? ||Q-P||^2 : 1.0)
//          = clamp( min_valid( x2 + y2 - 2 Q.P ), 0, 1.0 )
//
// Round-17: CONTROLLED REVERT to the best twice-measured configuration (round-0/r8
// pipeline: prep + LDS-staged band + combine, 87.3/87.8 us across two sessions)
// plus the one orthogonal verified improvement:
//   - prep reads Q ONCE (r9's fusion, correctness-verified in r9's passing run):
//     Qa-quant waves do both kh halves AND exact-fp32 |q|^2 (quad-reduce via
//     shfl_xor 16/32). Prep traffic 24 -> 17.5 MB, waves 6144 -> 3072 (grid 768).
//   - band + combine are byte-identical to round-0 (same Pq XOR-swizzled layout,
//     same Qa/yl/x2/part formats).
// POST-MORTEM r14-r16: four structurally different 2-dispatch variants (89.5-92.3)
// all sit within ~3 us — at the harness floor (256 MiB poison fill at ~80% HBM peak
// + reset memsets + launches); kernel-side deltas are sub-noise. The r8 pipeline is
// the only config measured below 88 (twice), so it is the right final state.
// Precision: single-plane i8 (q ~ h/32); dot err sigma ~0.13 vs ~45 budget. Sentinels:
// PEN_NM=2^22 > max|C|~1.6M scaled; masked C -> -2^28; mm init 2^30 (no i32 overflow).
//
// Workspace: yl 128K + x2 64K + Pq 2.10M + Qa 2.10M + part 1.57M ~= 6.0 MB.

#define HW   128
#define NC   100
#define MD   15
#define NOBJ 3
#define PIX  (HW * HW)
#define NOUT (PIX * NOBJ)          // 49152
#define PEN_NM (1 << 22)           // non-match penalty (units 1/512): > max |C| + 512
#define CSENT  (1 << 28)           // masked-slot C sentinel (subtracted -> huge cand)
#define IINIT  (1 << 30)           // running-min init

typedef __attribute__((ext_vector_type(4))) int intx4;   // 16 i8 / 4 i32 (MFMA A/B/C)

// h = rne(x*32) clamped to [-127,127]
__device__ inline intx4 quant_pack16(const float* v) {
    signed char b[16];
#pragma unroll
    for (int j = 0; j < 16; ++j) {
        int qi = __float2int_rn(v[j] * 32.f);
        b[j] = (signed char)max(-127, min(127, qi));
    }
    intx4 r;
#pragma unroll
    for (int w = 0; w < 4; ++w)
        r[w] = (b[4*w] & 255) | ((b[4*w+1] & 255) << 8) |
               ((b[4*w+2] & 255) << 16) | ((b[4*w+3] & 255) << 24);
    return r;
}

// ---------------- prep: quantize P (B image) + Q (A frags + x2), (y2,label) pairs --
// Waves: [0,2048) P+yl | [2048,3072) Q+x2.  Grid 768 x 256.
__global__ __launch_bounds__(256) void vos_prep(
    const float* __restrict__ P, const float* __restrict__ Q,
    const int* __restrict__ labels,
    signed char* __restrict__ Pq, signed char* __restrict__ Qa,
    int2* __restrict__ yl, float* __restrict__ x2)
{
    const int lane = threadIdx.x & 63;
    const int wid  = blockIdx.x * 4 + (threadIdx.x >> 6);

    if (wid < 2048) {
        // ---- P: wave = 8 pixels; lane = (pix8: lane>>3, chunk c: lane&7), k=c*16..+15
        const int pix = wid * 8 + (lane >> 3);
        const int col = pix & 127;
        const int c = lane & 7;
        const float* sp = P + (size_t)pix * NC;
        const int k0 = c * 16;
        float v[16];
#pragma unroll
        for (int c4 = 0; c4 < 4; ++c4) {
            float4 a = {0.f,0.f,0.f,0.f};
            if (k0 + c4 * 4 + 4 <= NC) a = *(const float4*)(sp + k0 + c4 * 4);
            v[c4*4+0]=a.x; v[c4*4+1]=a.y; v[c4*4+2]=a.z; v[c4*4+3]=a.w;
        }
        // B-image: pixel block 128 B = [chunk^(col&7) : 8][16 i8]
        *(intx4*)(Pq + (size_t)pix * 128 + ((c ^ (col & 7)) << 4)) = quant_pack16(v);
        float part = 0.f;                       // exact fp32 |p|^2
#pragma unroll
        for (int j = 0; j < 16; ++j) part = fmaf(v[j], v[j], part);
        part += __shfl_xor(part, 1); part += __shfl_xor(part, 2); part += __shfl_xor(part, 4);
        if ((lane & 7) == 0)
            yl[pix] = make_int2(__float2int_rn(part * 512.f), labels[pix]);  // (y2 in 1/512, label)
    } else {
        // ---- Q: wave = (row, tile); lane = (quad, m); both kh halves + exact x2.
        const int w2 = wid - 2048;              // 0..1023
        const int row = w2 >> 3, tile = w2 & 7;
        const int m = lane & 15, quad = lane >> 4;
        const int pix = row * HW + tile * 16 + m;
        const float* sp = Q + (size_t)pix * NC;
        signed char* dst = Qa + (size_t)((row * 8 + tile) * 2) * 1024 + lane * 16;
        float x2p = 0.f;
#pragma unroll
        for (int kh = 0; kh < 2; ++kh) {
            const int k0 = kh * 64 + quad * 16;
            float v[16];
#pragma unroll
            for (int c4 = 0; c4 < 4; ++c4) {
                float4 a = {0.f,0.f,0.f,0.f};
                if (k0 + c4 * 4 + 4 <= NC) a = *(const float4*)(sp + k0 + c4 * 4);
                v[c4*4+0]=a.x; v[c4*4+1]=a.y; v[c4*4+2]=a.z; v[c4*4+3]=a.w;
            }
#pragma unroll
            for (int j = 0; j < 16; ++j) x2p = fmaf(v[j], v[j], x2p);
            // A-frag image: [row][tile][kh] -> 1 KB lane-contiguous frags
            *(intx4*)(dst + kh * 1024) = quant_pack16(v);
        }
        // reduce |q|^2 over the 4 quads (lanes m, m+16, m+32, m+48)
        x2p += __shfl_xor(x2p, 16); x2p += __shfl_xor(x2p, 32);
        if (quad == 0) x2[pix] = x2p;
    }
}

// ---------------- async stage of one 16 KB Pq row into an LDS half ----------------
__device__ inline void stage_row(const signed char* __restrict__ Pq,
                                 signed char* dst, int r, int wv, int lane) {
    const signed char* src = Pq + (size_t)r * 16384 + wv * 4096;
    signed char* d = dst + wv * 4096;
#pragma unroll
    for (int it = 0; it < 4; ++it)
        __builtin_amdgcn_global_load_lds(
            (const __attribute__((address_space(1))) unsigned int*)(src + it * 1024 + lane * 16),
            (__attribute__((address_space(3))) unsigned int*)(d + it * 1024), 16, 0, 0);
}

// ---------------- main: banded i8-MFMA GEMM, pair-stepped, partial stores ----------
// Block: 256 thr (4 waves) = q-rows {i0,i0+1} x 128 cols; wave w: cols [32w,32w+32).
// Grid: 512 = 8 XCDs x 8 stripes x 8 r-chunks (4 rows each over [i0-15, i0+16]).
__global__ __launch_bounds__(256, 2) void vos_band(
    const signed char* __restrict__ Pq, const signed char* __restrict__ Qa,
    const int2* __restrict__ yl, const int* __restrict__ gt,
    float* __restrict__ part)
{
    __shared__ signed char Bs[2][2][16384];  // [pair-buf][row-in-pair], 64 KB
    __shared__ int2 yl_s[4 * 128];           // (y2*512, label) for the chunk rows

    const int tid  = threadIdx.x;
    const int lane = tid & 63;
    const int wv   = tid >> 6;               // 0..3
    const int quad = lane >> 4;
    const int n    = lane & 15;
    const int j0w  = wv * 32;

    // XCD grouping (b&7 = XCD round-robin heuristic): 8 contiguous stripes/XCD
    // -> per-XCD Pq footprint ~46 rows x 16 KB = 736 KB << 4 MiB L2.
    const int b      = blockIdx.x;
    const int xcd    = b & 7;
    const int wi     = b >> 3;               // 0..63
    const int stripe = xcd * 8 + (wi & 7);   // 0..63
    const int ck     = wi >> 3;              // 0..7
    const int i0     = stripe * 2;
    const int rbase  = i0 - MD + ck * 4;     // 8 chunks x 4 rows = [i0-15, i0+16] exactly
    const int rlo    = max(rbase, 0);
    const int rhi    = min(rbase + 4, HW);
    const int np     = (rhi > rlo) ? ((rhi - rlo + 1) >> 1) : 0;   // pair-steps

    const int g0 = gt[0], g1 = gt[1], g2 = gt[2];

    // ---- first pair DMA immediately
    if (np > 0) {
        stage_row(Pq, &Bs[0][0][0], rlo, wv, lane);
        if (rlo + 1 < rhi) stage_row(Pq, &Bs[0][1][0], rlo + 1, wv, lane);
    }

    // ---- stage (y2,label) pairs for the chunk rows (unused slots never read)
    for (int t = tid; t < 4 * 128; t += 256) {
        int rr = t >> 7, c = t & 127, r = rbase + rr;
        if ((unsigned)r < (unsigned)HW) yl_s[t] = yl[r * HW + c];
    }

    // ---- A fragments from pre-quantized Qa (coalesced b128, zero VALU)
    intx4 Af[2][2][2];                       // [uc][ur][kh]
#pragma unroll
    for (int uc = 0; uc < 2; ++uc)
#pragma unroll
    for (int ur = 0; ur < 2; ++ur) {
        const signed char* bse = Qa + (size_t)((i0 + ur) * 8 + wv * 2 + uc) * 2048;
#pragma unroll
        for (int kh = 0; kh < 2; ++kh)
            Af[uc][ur][kh] = *(const intx4*)(bse + kh * 1024 + lane * 16);
    }

    // Band masks for triangular side tiles: offset = 16*du + n - m, valid |off|<=15.
    bool bgt[4], blt[4];
#pragma unroll
    for (int reg = 0; reg < 4; ++reg) {
        int m = quad * 4 + reg;
        bgt[reg] = n > m;   // du = -1
        blt[reg] = n < m;   // du = +1
    }

    // Integer running mins of (pen*512 - C) per object (C = 1024*dot; scale 1/512).
    int mm[2][2][4][NOBJ];
#pragma unroll
    for (int uc = 0; uc < 2; ++uc)
#pragma unroll
    for (int ur = 0; ur < 2; ++ur)
#pragma unroll
    for (int reg = 0; reg < 4; ++reg) {
        mm[uc][ur][reg][0] = IINIT; mm[uc][ur][reg][1] = IINIT; mm[uc][ur][reg][2] = IINIT;
    }

    __syncthreads();   // yl_s visible; first pair DMA drained

    for (int pi = 0; pi < np; ++pi) {
        const int ra = rlo + 2 * pi;
        const int rb = ra + 1;                         // may equal rhi (then masked)
        // ---- prefetch next pair into the other buffer (drained at end barrier with
        // this step's compute in flight behind it)
        if (pi + 1 < np) {
            const int r2 = ra + 2;
            stage_row(Pq, &Bs[(pi + 1) & 1][0][0], r2, wv, lane);
            if (r2 + 1 < rhi) stage_row(Pq, &Bs[(pi + 1) & 1][1][0], r2 + 1, wv, lane);
        }

        const signed char* BA = &Bs[pi & 1][0][0];
        const signed char* BB = &Bs[pi & 1][1][0];
        const bool hasB = rb < rhi;
        bool rvA[2], rvB[2];                           // wave-uniform row validity per ur
        rvA[0] = (unsigned)(ra - i0 + MD)     <= 2u * MD;
        rvA[1] = (unsigned)(ra - i0 - 1 + MD) <= 2u * MD;
        rvB[0] = hasB && ((unsigned)(rb - i0 + MD)     <= 2u * MD);
        rvB[1] = hasB && ((unsigned)(rb - i0 - 1 + MD) <= 2u * MD);
        const int rrA = (ra - rbase) * 128;
        const int rrB = (min(rb, rhi - 1) - rbase) * 128;   // safe index; masked if !hasB

#pragma unroll
        for (int t = 0; t < 4; ++t) {
            const int base = j0w + 16 * (t - 1);
            if (base < 0 || base >= HW) continue;      // wave-uniform edge skip

            const int pcol = base + n;
            int2 ylA = yl_s[rrA + pcol];
            int2 ylB = yl_s[rrB + pcol];
            int pA0 = (ylA.y == g0) ? ylA.x : PEN_NM;
            int pA1 = (ylA.y == g1) ? ylA.x : PEN_NM;
            int pA2 = (ylA.y == g2) ? ylA.x : PEN_NM;
            int pB0 = (ylB.y == g0) ? ylB.x : PEN_NM;
            int pB1 = (ylB.y == g1) ? ylB.x : PEN_NM;
            int pB2 = (ylB.y == g2) ? ylB.x : PEN_NM;

            intx4 CA[2][2], CB[2][2];
#pragma unroll
            for (int uc = 0; uc < 2; ++uc)
#pragma unroll
            for (int ur = 0; ur < 2; ++ur) {
                CA[uc][ur] = (intx4){0,0,0,0};
                CB[uc][ur] = (intx4){0,0,0,0};
            }

#pragma unroll
            for (int kh = 0; kh < 2; ++kh) {
                const int off = pcol * 128 + (((kh * 4 + quad) ^ (pcol & 7)) << 4);
                intx4 bvA = *(const intx4*)(BA + off);
                intx4 bvB = *(const intx4*)(BB + off);   // garbage if !hasB -> masked
#pragma unroll
                for (int uc = 0; uc < 2; ++uc) {
                    if (uc == 0 && t == 3) continue;     // uc0 uses t in {0,1,2}
                    if (uc == 1 && t == 0) continue;     // uc1 uses t in {1,2,3}
#pragma unroll
                    for (int ur = 0; ur < 2; ++ur) {
                        CA[uc][ur] = __builtin_amdgcn_mfma_i32_16x16x64_i8(Af[uc][ur][kh], bvA, CA[uc][ur], 0, 0, 0);
                        CB[uc][ur] = __builtin_amdgcn_mfma_i32_16x16x64_i8(Af[uc][ur][kh], bvB, CB[uc][ur], 0, 0, 0);
                    }
                }
            }

            // ---- epilogue: cand = pen - C (1/512 units); both rows -> one min3 chain
#pragma unroll
            for (int uc = 0; uc < 2; ++uc) {
                if (uc == 0 && t == 3) continue;
                if (uc == 1 && t == 0) continue;
                const int du = t - 1 - uc;               // -1, 0, +1 (compile-time)
#pragma unroll
                for (int ur = 0; ur < 2; ++ur) {
#pragma unroll
                    for (int reg = 0; reg < 4; ++reg) {
                        bool tri = (du == 0) | (du == -1 ? bgt[reg] : blt[reg]);
                        bool okA = rvA[ur] & tri;
                        bool okB = rvB[ur] & tri;
                        int cA = okA ? CA[uc][ur][reg] : -CSENT;
                        int cB = okB ? CB[uc][ur][reg] : -CSENT;
                        mm[uc][ur][reg][0] = min(min(mm[uc][ur][reg][0], pA0 - cA), pB0 - cB);
                        mm[uc][ur][reg][1] = min(min(mm[uc][ur][reg][1], pA1 - cA), pB1 - cB);
                        mm[uc][ur][reg][2] = min(min(mm[uc][ur][reg][2], pA2 - cA), pB2 - cB);
                    }
                }
            }
        }
        __syncthreads();   // drains prefetch DMA; next step reads the other buffer
    }

    // ---- min-reduce across the 16 N-lanes (int butterfly)
#pragma unroll
    for (int s = 1; s < 16; s <<= 1) {
#pragma unroll
        for (int uc = 0; uc < 2; ++uc)
#pragma unroll
        for (int ur = 0; ur < 2; ++ur)
#pragma unroll
        for (int reg = 0; reg < 4; ++reg)
#pragma unroll
        for (int o = 0; o < NOBJ; ++o)
            mm[uc][ur][reg][o] = min(mm[uc][ur][reg][o], __shfl_xor(mm[uc][ur][reg][o], s));
    }

    // ---- LDS transpose (reuse Bs; all DMA drained, no more Bs reads) then 192
    // coalesced float4 stores: block's 768 floats are contiguous in part.
    float* ps = (float*)&Bs[0][0][0];
    if (n == 0) {
#pragma unroll
        for (int uc = 0; uc < 2; ++uc)
#pragma unroll
        for (int ur = 0; ur < 2; ++ur)
#pragma unroll
        for (int reg = 0; reg < 4; ++reg) {
            const int qcol = j0w + 16 * uc + quad * 4 + reg;
#pragma unroll
            for (int o = 0; o < NOBJ; ++o)
                ps[(ur * 128 + qcol) * 3 + o] = (float)mm[uc][ur][reg][o];
        }
    }
    __syncthreads();
    if (tid < 192) {
        float4 v = *(const float4*)(ps + tid * 4);
        *(float4*)(part + (size_t)ck * NOUT + i0 * 384 + tid * 4) = v;
    }
}

// ---------------- combine: 8-way min over chunks + x2 + clamp, coalesced ----------
__global__ __launch_bounds__(256) void vos_combine(
    const float* __restrict__ part, const float* __restrict__ x2,
    float* __restrict__ out)
{
    const int t = blockIdx.x * 256 + threadIdx.x;    // 0..49151
    float v = part[t];
#pragma unroll
    for (int ck = 1; ck < 8; ++ck) v = fminf(v, part[ck * NOUT + t]);
    v = v * (1.f / 512.f) + x2[t / 3];               // units 1/512; add exact |q|^2
    out[t] = fminf(fmaxf(v, 0.f), 1.0f);             // 1.0 = mask padding
}

extern "C" void kernel_launch(void* const* d_in, const int* in_sizes, int n_in,
                              void* d_out, int out_size, void* d_ws, size_t ws_size,
                              hipStream_t stream) {
    const float* P      = (const float*)d_in[0];   // prev_frame_embedding [128,128,100]
    const float* Q      = (const float*)d_in[1];   // query_embedding      [128,128,100]
    const int*   labels = (const int*)d_in[2];     // prev_frame_labels    [128,128,1]
    const int*   gt     = (const int*)d_in[3];     // gt_ids [3]
    // d_in[4] = max_distance (always 15; compiled for MD=15)

    // Workspace layout (~6.0 MB):
    int2*  yl = (int2*)d_ws;                                    // 128 KB (y2*512, label)
    float* x2 = (float*)(yl + PIX);                             //  64 KB (exact fp32)
    signed char* Pq = (signed char*)(x2 + PIX);                 // 2.10 MB (B image)
    signed char* Qa = Pq + (size_t)PIX * 128;                   // 2.10 MB (A frags)
    float* part = (float*)(Qa + (size_t)PIX * 128);             // 1.57 MB (8 x 49152)
    float* out = (float*)d_out;

    vos_prep<<<768, 256, 0, stream>>>(P, Q, labels, Pq, Qa, yl, x2);
    vos_band<<<512, 256, 0, stream>>>(Pq, Qa, yl, gt, part);
    vos_combine<<<NOUT / 256, 256, 0, stream>>>(part, x2, out);
}